// Round 5
// baseline (2821.760 us; speedup 1.0000x reference)
//
#include <hip/hip_runtime.h>
#include <hip/hip_bf16.h>

typedef __bf16  bf16x8  __attribute__((ext_vector_type(8)));
typedef short   short8_t __attribute__((ext_vector_type(8)));
typedef float   float4_t __attribute__((ext_vector_type(4)));

#define MFMA(a, b, c) __builtin_amdgcn_mfma_f32_16x16x32_bf16((a), (b), (c), 0, 0, 0)

#define LOG2E      1.4426950408889634f
#define TWO_LOG2E  2.8853900817779268f

// LDS-only barrier: drain LDS ops (publish + WAR safety), do NOT drain vmcnt —
// global trajectory stores are to disjoint addresses and never cross-wave.
#define BAR() do {                                            \
    asm volatile("s_waitcnt lgkmcnt(0)" ::: "memory");        \
    __builtin_amdgcn_s_barrier();                             \
    asm volatile("" ::: "memory");                            \
  } while (0)

__device__ __forceinline__ unsigned short f2bf(float f) {
  unsigned u = __builtin_bit_cast(unsigned, f);
  unsigned r = ((u >> 16) & 1u) + 0x7FFFu;   // round-to-nearest-even
  return (unsigned short)((u + r) >> 16);
}
// x pre-scaled by LOG2E
__device__ __forceinline__ float sig2(float x) {
  return __builtin_amdgcn_rcpf(1.f + __builtin_amdgcn_exp2f(-x));
}
// x pre-scaled by 2*LOG2E
__device__ __forceinline__ float tanh2s(float x) {
  return 1.f - 2.f * __builtin_amdgcn_rcpf(1.f + __builtin_amdgcn_exp2f(x));
}

// 256 blocks x 512 threads (8 waves), 32 batch rows/block. Wave w owns hidden
// units [16w,16w+16). h1f is DOUBLE-BUFFERED (rp = t&1 read buf, wp = other);
// x A-frags alias the first 2 KiB of the wp buffer (h1f(t-2) is dead there:
// last read at step t-1 R3; R3(t) overwrites it only after R2(t) read xf).
// Per step, 3 lgkm-only barriers:
//   R1: cell0 h-part MFMA (32, reads h0f(t-1))
//       + proj (w<4, t>0: reads h1f[rp] -> x(t); writes xf -> h1f[wp] corner;
//         issues out stores, which drain lazily -- no vmcnt at barriers)
//   B1  (WAR h0f(t-1); xf publish)
//   R2: x-part MFMA (8, reads xf) + act0 m-interleaved + h0f(t) writes
//   B2  (h0f(t) publish)
//   R3: cell1 MFMA (64, reads h0f(t), h1f[rp]) + act1 m-interleaved,
//       writing h1(t) directly into h1f[wp] (no WAR: other buffer)
//   B3  (h1f[wp] publish)
__global__ __launch_bounds__(512, 2) void lstm_roll(
    const float* __restrict__ x0,  const float* __restrict__ W0,
    const float* __restrict__ b0v, const float* __restrict__ W1,
    const float* __restrict__ b1v, const float* __restrict__ Wout,
    const float* __restrict__ bout, const float* __restrict__ dts,
    const int* __restrict__ nsp,   float* __restrict__ out)
{
  __shared__ __align__(16) unsigned short w0h[8 * 4 * 4 * 512];  // 128 KiB W0 h-part B-frags [w][g][kt]
  __shared__ __align__(16) unsigned short woutF[2 * 4 * 512];    //   8 KiB Wout B-frags [n][kt] (dts*DT folded)
  __shared__ __align__(16) unsigned short h0f[4 * 2 * 512];      //   8 KiB h0 A-frags [kt][m]
  __shared__ __align__(16) unsigned short h1f[2 * 4 * 2 * 512];  //  16 KiB h1 A-frags, double-buffered

  const int tid = threadIdx.x;
  const int w   = tid >> 6;
  const int l   = tid & 63;
  const int lm  = l & 15;
  const int lh  = l >> 4;
  const int T   = nsp[0];
  const long rowStride = (long)(T + 1) * 32;
  const long bbase = (long)blockIdx.x * 32;

  // ---------------- weight gather / packing (once) ----------------
  bf16x8 w0x[4];       // W0 x-part B-frags (K=32)
  bf16x8 w1f[4][8];    // W1 B-frags (K=256; kt 0..3 h0-part, 4..7 h1-part)
  #pragma unroll
  for (int g = 0; g < 4; ++g) {
    const float sc = (g == 2) ? TWO_LOG2E : LOG2E;
    const int col = g * 128 + w * 16 + lm;
    {
      short8_t t8;
      #pragma unroll
      for (int e = 0; e < 8; ++e) t8[e] = (short)f2bf(sc * W0[(lh * 8 + e) * 512 + col]);
      w0x[g] = __builtin_bit_cast(bf16x8, t8);
    }
    #pragma unroll
    for (int kt = 0; kt < 8; ++kt) {
      short8_t t8;
      #pragma unroll
      for (int e = 0; e < 8; ++e) t8[e] = (short)f2bf(sc * W1[(kt * 32 + lh * 8 + e) * 512 + col]);
      w1f[g][kt] = __builtin_bit_cast(bf16x8, t8);
    }
    #pragma unroll
    for (int kt = 0; kt < 4; ++kt) {
      const int base = (((w * 4 + g) * 4) + kt) * 512 + l * 8;
      #pragma unroll
      for (int e = 0; e < 8; ++e)
        w0h[base + e] = f2bf(sc * W0[(32 + kt * 32 + lh * 8 + e) * 512 + col]);
    }
  }
  { // Wout B-frags with dts*DT folded in; 8 frags, one per wave
    const int n = w & 1, kt = w >> 1;
    if (kt < 4) {
      const float csc = dts[n * 16 + lm] * 0.01f;
      const int base = (n * 4 + kt) * 512 + l * 8;
      #pragma unroll
      for (int e = 0; e < 8; ++e)
        woutF[base + e] = f2bf(csc * Wout[(kt * 32 + lh * 8 + e) * 32 + (n * 16 + lm)]);
    }
  }
  float b0r[4], b1r[4];
  #pragma unroll
  for (int g = 0; g < 4; ++g) {
    const float sc = (g == 2) ? TWO_LOG2E : LOG2E;
    b0r[g] = sc * b0v[g * 128 + w * 16 + lm];
    b1r[g] = sc * b1v[g * 128 + w * 16 + lm];
  }

  // proj mapping: waves 0..3 own (m_c, n_c) output quadrant
  const int m_c = w & 1, n_c = (w >> 1) & 1;
  float boutr = 0.f, xr[4] = {0.f, 0.f, 0.f, 0.f};
  long obase0 = 0;
  int  xfbase = 0;
  if (w < 4) {
    boutr = bout[n_c * 16 + lm] * dts[n_c * 16 + lm] * 0.01f;
    const int kin = n_c * 16 + lm;
    xfbase = m_c * 512 + (lh * 4 + 16 * (kin >> 3)) * 8 + (kin & 7);
    obase0 = (bbase + m_c * 16 + lh * 4) * rowStride + (n_c * 16 + lm);
    #pragma unroll
    for (int r = 0; r < 4; ++r) {
      xr[r] = x0[(bbase + m_c * 16 + lh * 4 + r) * 32 + n_c * 16 + lm];
      out[obase0 + r * rowStride] = xr[r];               // trajectory t = 0
      h1f[4096 + xfbase + r * 8] = f2bf(xr[r]);          // xf(0) in wp(0)=1 corner
    }
  }
  for (int i = tid; i < 4 * 2 * 512; i += 512) { h0f[i] = 0; h1f[i] = 0; }  // h0f + h1f buf0 zeros

  // h-write scatter base (fragment layout; same for h0f/h1f)
  const int hwb = ((w >> 1) * 2) * 512 +
                  (lh * 4 + 16 * (2 * (w & 1) + ((lm >> 3) & 1))) * 8 + (lm & 7);

  float4_t c0[2], c1[2];
  #pragma unroll
  for (int m = 0; m < 2; ++m) {
    c0[m] = (float4_t){0.f, 0.f, 0.f, 0.f};
    c1[m] = (float4_t){0.f, 0.f, 0.f, 0.f};
  }

  BAR();   // publish w0h, woutF, h0f/h1f0 zeros, xf(0)

  #pragma unroll 1
  for (int t = 0; t < T; ++t) {
    const int rpo = (t & 1) * 4096;      // h1f read-buffer offset (h1(t-1))
    const int wpo = 4096 - rpo;          // h1f write-buffer offset (xf corner + h1(t))

    // ============ R1: cell0 h-part + proj(h1(t-1)) ============
    float4_t acc0[2][4];
    #pragma unroll
    for (int g = 0; g < 4; ++g) {
      acc0[0][g] = (float4_t){b0r[g], b0r[g], b0r[g], b0r[g]};
      acc0[1][g] = (float4_t){b0r[g], b0r[g], b0r[g], b0r[g]};
    }
    #pragma unroll
    for (int kt = 0; kt < 4; ++kt) {
      const bf16x8 a0 = *(const bf16x8*)&h0f[(kt * 2 + 0) * 512 + l * 8];
      const bf16x8 a1 = *(const bf16x8*)&h0f[(kt * 2 + 1) * 512 + l * 8];
      #pragma unroll
      for (int g = 0; g < 4; ++g) {
        const bf16x8 bw = *(const bf16x8*)&w0h[(((w * 4 + g) * 4) + kt) * 512 + l * 8];
        acc0[0][g] = MFMA(a0, bw, acc0[0][g]);
        acc0[1][g] = MFMA(a1, bw, acc0[1][g]);
      }
    }
    if (w < 4 && t > 0) {   // proj: x(t) = x(t-1) + h1(t-1) @ WoutF
      float4_t dacc = (float4_t){boutr, boutr, boutr, boutr};
      #pragma unroll
      for (int kt = 0; kt < 4; ++kt) {
        const bf16x8 a  = *(const bf16x8*)&h1f[rpo + (kt * 2 + m_c) * 512 + l * 8];
        const bf16x8 bw = *(const bf16x8*)&woutF[(n_c * 4 + kt) * 512 + l * 8];
        dacc = MFMA(a, bw, dacc);
      }
      const long ob = obase0 + (long)t * 32;
      #pragma unroll
      for (int r = 0; r < 4; ++r) {
        xr[r] += dacc[r];
        h1f[wpo + xfbase + r * 8] = f2bf(xr[r]);   // xf(t) into dead wp corner
        out[ob + r * rowStride] = xr[r];           // drains lazily (no vmcnt at BAR)
      }
    }
    BAR();   // B1: h0f(t-1) WAR done; xf(t) published

    // ============ R2: x-part + act0 (m-interleaved) + h0f writes ============
    {
      const bf16x8 ax0 = *(const bf16x8*)&h1f[wpo + l * 8];
      #pragma unroll
      for (int g = 0; g < 4; ++g) acc0[0][g] = MFMA(ax0, w0x[g], acc0[0][g]);
      const bf16x8 ax1 = *(const bf16x8*)&h1f[wpo + 512 + l * 8];
      // act0 m=0 overlaps m=1 x-part MFMAs
      #pragma unroll
      for (int r = 0; r < 4; ++r) {
        const float iv = sig2(acc0[0][0][r]);
        const float fv = sig2(acc0[0][1][r]);
        const float gv = tanh2s(acc0[0][2][r]);
        const float ov = sig2(acc0[0][3][r]);
        const float cc = fv * c0[0][r] + iv * gv;
        c0[0][r] = cc;
        h0f[hwb + r * 8] = f2bf(ov * tanh2s(cc * TWO_LOG2E));
      }
      #pragma unroll
      for (int g = 0; g < 4; ++g) acc0[1][g] = MFMA(ax1, w0x[g], acc0[1][g]);
      #pragma unroll
      for (int r = 0; r < 4; ++r) {
        const float iv = sig2(acc0[1][0][r]);
        const float fv = sig2(acc0[1][1][r]);
        const float gv = tanh2s(acc0[1][2][r]);
        const float ov = sig2(acc0[1][3][r]);
        const float cc = fv * c0[1][r] + iv * gv;
        c0[1][r] = cc;
        h0f[hwb + 512 + r * 8] = f2bf(ov * tanh2s(cc * TWO_LOG2E));
      }
    }
    BAR();   // B2: h0f(t) published

    // ============ R3: cell1 + act1 (m-interleaved), write h1f[wp] ============
    float4_t acc1[2][4];
    #pragma unroll
    for (int g = 0; g < 4; ++g) {
      acc1[0][g] = (float4_t){b1r[g], b1r[g], b1r[g], b1r[g]};
      acc1[1][g] = (float4_t){b1r[g], b1r[g], b1r[g], b1r[g]};
    }
    // m=0 accumulation (h0-part then h1-part)
    #pragma unroll
    for (int kt = 0; kt < 4; ++kt) {
      const bf16x8 a = *(const bf16x8*)&h0f[(kt * 2 + 0) * 512 + l * 8];
      #pragma unroll
      for (int g = 0; g < 4; ++g) acc1[0][g] = MFMA(a, w1f[g][kt], acc1[0][g]);
    }
    #pragma unroll
    for (int kt = 0; kt < 4; ++kt) {
      const bf16x8 a = *(const bf16x8*)&h1f[rpo + (kt * 2 + 0) * 512 + l * 8];
      #pragma unroll
      for (int g = 0; g < 4; ++g) acc1[0][g] = MFMA(a, w1f[g][kt + 4], acc1[0][g]);
    }
    // act1 m=0 overlaps m=1 MFMAs; write straight to wp buffer (no WAR)
    #pragma unroll
    for (int r = 0; r < 4; ++r) {
      const float iv = sig2(acc1[0][0][r]);
      const float fv = sig2(acc1[0][1][r]);
      const float gv = tanh2s(acc1[0][2][r]);
      const float ov = sig2(acc1[0][3][r]);
      const float cc = fv * c1[0][r] + iv * gv;
      c1[0][r] = cc;
      h1f[wpo + hwb + r * 8] = f2bf(ov * tanh2s(cc * TWO_LOG2E));
    }
    #pragma unroll
    for (int kt = 0; kt < 4; ++kt) {
      const bf16x8 a = *(const bf16x8*)&h0f[(kt * 2 + 1) * 512 + l * 8];
      #pragma unroll
      for (int g = 0; g < 4; ++g) acc1[1][g] = MFMA(a, w1f[g][kt], acc1[1][g]);
    }
    #pragma unroll
    for (int kt = 0; kt < 4; ++kt) {
      const bf16x8 a = *(const bf16x8*)&h1f[rpo + (kt * 2 + 1) * 512 + l * 8];
      #pragma unroll
      for (int g = 0; g < 4; ++g) acc1[1][g] = MFMA(a, w1f[g][kt + 4], acc1[1][g]);
    }
    #pragma unroll
    for (int r = 0; r < 4; ++r) {
      const float iv = sig2(acc1[1][0][r]);
      const float fv = sig2(acc1[1][1][r]);
      const float gv = tanh2s(acc1[1][2][r]);
      const float ov = sig2(acc1[1][3][r]);
      const float cc = fv * c1[1][r] + iv * gv;
      c1[1][r] = cc;
      h1f[wpo + hwb + 512 + r * 8] = f2bf(ov * tanh2s(cc * TWO_LOG2E));
    }
    BAR();   // B3: h1f(t) published
  }

  // ============ Epilogue: x(T) from h1(T-1) ============
  if (w < 4) {
    const int fin = (T & 1) * 4096;   // buffer written at step T-1
    float4_t dacc = (float4_t){boutr, boutr, boutr, boutr};
    #pragma unroll
    for (int kt = 0; kt < 4; ++kt) {
      const bf16x8 a  = *(const bf16x8*)&h1f[fin + (kt * 2 + m_c) * 512 + l * 8];
      const bf16x8 bw = *(const bf16x8*)&woutF[(n_c * 4 + kt) * 512 + l * 8];
      dacc = MFMA(a, bw, dacc);
    }
    const long ob = obase0 + (long)T * 32;
    #pragma unroll
    for (int r = 0; r < 4; ++r) {
      xr[r] += dacc[r];
      out[ob + r * rowStride] = xr[r];
    }
  }
}

extern "C" void kernel_launch(void* const* d_in, const int* in_sizes, int n_in,
                              void* d_out, int out_size, void* d_ws, size_t ws_size,
                              hipStream_t stream) {
  (void)n_in; (void)out_size; (void)d_ws; (void)ws_size;
  const float* x0   = (const float*)d_in[0];
  const float* W0   = (const float*)d_in[1];
  const float* b0   = (const float*)d_in[2];
  const float* W1   = (const float*)d_in[3];
  const float* b1   = (const float*)d_in[4];
  const float* Wout = (const float*)d_in[5];
  const float* bout = (const float*)d_in[6];
  const float* dts  = (const float*)d_in[7];
  const int*   nsp  = (const int*)d_in[8];
  float* out = (float*)d_out;

  const int B    = in_sizes[0] / 32;   // 8192
  const int grid = B / 32;             // 256 blocks, 32 batch rows each
  lstm_roll<<<dim3(grid), dim3(512), 0, stream>>>(x0, W0, b0, W1, b1, Wout, bout, dts, nsp, out);
}